// Round 5
// baseline (142.784 us; speedup 1.0000x reference)
//
#include <hip/hip_runtime.h>

#define DIM   512
#define EE    1024      // E = expand*dim
#define NS    16        // d_state
#define BB    4
#define LL    2048
#define MM    (BB*LL)   // 8192 token rows
#define NC    64        // scan chunks
#define CL    32        // chunk length (NC*CL == LL)

typedef __bf16 bf16x8 __attribute__((ext_vector_type(8)));
typedef __bf16 bf16x4 __attribute__((ext_vector_type(4)));
typedef float  f32x4  __attribute__((ext_vector_type(4)));
typedef _Float16 f16x8 __attribute__((ext_vector_type(8)));

static __device__ __forceinline__ float sigmoidf_(float x) {
    return 1.0f / (1.0f + __expf(-x));
}

// async global->LDS, 16B per lane; LDS base must be wave-uniform (HW adds lane*16)
#define GLOAD(gp, lp) __builtin_amdgcn_global_load_lds( \
    (const __attribute__((address_space(1))) unsigned int*)(const void*)(gp), \
    (__attribute__((address_space(3))) unsigned int*)(void*)(lp), 16, 0, 0)

// ---------------------------------------------------------------- converts
__global__ __launch_bounds__(256) void k_tobf(
    const float* __restrict__ x, const float* __restrict__ Win,
    const float* __restrict__ Wout, const float* __restrict__ Bp,
    __bf16* __restrict__ xbf, __bf16* __restrict__ winbf,
    __bf16* __restrict__ woutbf, __bf16* __restrict__ bpT)
{
    int g = blockIdx.x * 256 + threadIdx.x;
    const int nx4 = MM * DIM / 4;        // 1048576
    const int nw4 = 2 * EE * DIM / 4;    // 262144
    const int no4 = DIM * EE / 4;        // 131072
    if (g < nx4) {
        f32x4 v = ((const f32x4*)x)[g];
        bf16x4 o; for (int j = 0; j < 4; ++j) o[j] = (__bf16)v[j];
        ((bf16x4*)xbf)[g] = o;
    } else if (g < nx4 + nw4) {
        int i = g - nx4;
        f32x4 v = ((const f32x4*)Win)[i];
        bf16x4 o; for (int j = 0; j < 4; ++j) o[j] = (__bf16)v[j];
        ((bf16x4*)winbf)[i] = o;
    } else if (g < nx4 + nw4 + no4) {
        int i = g - nx4 - nw4;
        f32x4 v = ((const f32x4*)Wout)[i];
        bf16x4 o; for (int j = 0; j < 4; ++j) o[j] = (__bf16)v[j];
        ((bf16x4*)woutbf)[i] = o;
    } else {
        int i = g - nx4 - nw4 - no4;     // [0, 16384)
        int e = i >> 4, n = i & 15;
        bpT[n * EE + e] = (__bf16)Bp[i];
    }
}

// ---------------------------------------------------------------- GEMM1 (m97-style, 128x64 dual-half)
__global__ __launch_bounds__(256, 4) void k_gemm1(
    const __bf16* __restrict__ Abf,   // [8192,512]
    const __bf16* __restrict__ Wbf,   // [2048,512]
    __bf16* __restrict__ xs)          // [8192,1024]
{
    __shared__ __bf16 sA[128 * 64];   // 16KB
    __shared__ __bf16 sB0[64 * 64];   // 8KB
    __shared__ __bf16 sB1[64 * 64];   // 8KB

    int bid = blockIdx.x;
    int swz = (bid & 7) * 128 + (bid >> 3);  // XCD-chunked (1024 % 8 == 0)
    int bm = swz >> 4;          // 0..63
    int bn = swz & 15;          // 0..15

    int t = threadIdx.x;
    int lane = t & 63;
    int w = t >> 6;
    int wm = (w >> 1) * 64;
    int wn = (w & 1) * 32;
    int r15 = lane & 15;
    int kq = lane >> 4;

    const __bf16* Agb  = Abf + (bm * 128) * DIM;
    const __bf16* B0gb = Wbf + (bn * 64) * DIM;
    const __bf16* B1gb = Wbf + (1024 + bn * 64) * DIM;

    f32x4 accx[4][2] = {};
    f32x4 accg[4][2] = {};

    for (int kt = 0; kt < 8; ++kt) {
        #pragma unroll
        for (int i_ = 0; i_ < 4; ++i_) {
            int c_ = i_ * 256 + t;
            int row_ = c_ >> 3;
            int ss_ = (c_ & 7) ^ (row_ & 7);
            GLOAD(Agb + kt * 64 + row_ * DIM + ss_ * 8, sA + (i_ * 256 + w * 64) * 8);
        }
        #pragma unroll
        for (int i_ = 0; i_ < 2; ++i_) {
            int c_ = i_ * 256 + t;
            int row_ = c_ >> 3;
            int ss_ = (c_ & 7) ^ (row_ & 7);
            GLOAD(B0gb + kt * 64 + row_ * DIM + ss_ * 8, sB0 + (i_ * 256 + w * 64) * 8);
            GLOAD(B1gb + kt * 64 + row_ * DIM + ss_ * 8, sB1 + (i_ * 256 + w * 64) * 8);
        }
        __syncthreads();
        #pragma unroll
        for (int ks = 0; ks < 2; ++ks) {
            int kcs = ks * 4 + kq;       // k-slot 0..7
            bf16x8 a[4], b0[2], b1[2];
            #pragma unroll
            for (int m = 0; m < 4; ++m) {
                int r = wm + m * 16 + r15;
                a[m] = *(const bf16x8*)&sA[r * 64 + (kcs ^ (r & 7)) * 8];
            }
            #pragma unroll
            for (int n = 0; n < 2; ++n) {
                int r = wn + n * 16 + r15;
                b0[n] = *(const bf16x8*)&sB0[r * 64 + (kcs ^ (r & 7)) * 8];
                b1[n] = *(const bf16x8*)&sB1[r * 64 + (kcs ^ (r & 7)) * 8];
            }
            #pragma unroll
            for (int m = 0; m < 4; ++m)
                #pragma unroll
                for (int n = 0; n < 2; ++n) {
                    accx[m][n] = __builtin_amdgcn_mfma_f32_16x16x32_bf16(a[m], b0[n], accx[m][n], 0, 0, 0);
                    accg[m][n] = __builtin_amdgcn_mfma_f32_16x16x32_bf16(a[m], b1[n], accg[m][n], 0, 0, 0);
                }
        }
        __syncthreads();
    }

    #pragma unroll
    for (int m = 0; m < 4; ++m)
        #pragma unroll
        for (int n = 0; n < 2; ++n)
            #pragma unroll
            for (int r = 0; r < 4; ++r) {
                int row = bm * 128 + wm + m * 16 + (lane >> 4) * 4 + r;
                int col = bn * 64 + wn + n * 16 + r15;
                float xv = accx[m][n][r];
                float gv = accg[m][n][r];
                xs[row * EE + col] = (__bf16)(xv * sigmoidf_(gv));
            }
}

// ---------------------------------------------------------------- fused depthwise conv + silu + delta projection
// (u is NOT materialized to global anymore; scan kernels recompute it from xs)
__global__ __launch_bounds__(256) void k_convdelta(
    const __bf16* __restrict__ xs, const float* __restrict__ Wc,
    const __bf16* __restrict__ bpT,
    float* __restrict__ delta)
{
    __shared__ __bf16 uS[8][1032];   // padded: row stride 2064B -> 4-bank offset/row
    __shared__ float red[4][256];
    int bid = blockIdx.x;            // 1024
    int r0b = bid * 8;
    int t = threadIdx.x;
    int cg_ = t & 127, rh = t >> 7;  // rh 0/1 -> 4 rows each
    int e8 = cg_ << 3;
    int rr0 = r0b + rh * 4;
    int l0 = rr0 & (LL - 1);

    f32x4 wj[8];
    #pragma unroll
    for (int j = 0; j < 8; ++j) wj[j] = *(const f32x4*)&Wc[(e8 + j) * 4];
    bf16x8 z = {};
    bf16x8 win[7];
    #pragma unroll
    for (int i = 0; i < 7; ++i) {
        win[i] = (l0 + i >= 3) ? *(const bf16x8*)&xs[(rr0 + i - 3) * EE + e8] : z;
    }
    #pragma unroll
    for (int i = 0; i < 4; ++i) {
        bf16x8 out;
        #pragma unroll
        for (int j = 0; j < 8; ++j) {
            float a = (float)win[i][j] * wj[j][0] + (float)win[i + 1][j] * wj[j][1]
                    + (float)win[i + 2][j] * wj[j][2] + (float)win[i + 3][j] * wj[j][3];
            out[j] = (__bf16)(a * sigmoidf_(a));
        }
        *(bf16x8*)&uS[rh * 4 + i][e8] = out;
    }
    __syncthreads();

    // delta phase
    int lane = t & 63, w = t >> 6;
    int ar = lane & 15, kc = (lane >> 4) << 3;
    f32x4 acc = {};
    #pragma unroll
    for (int k0 = 0; k0 < 256; k0 += 32) {
        int k = w * 256 + k0 + kc;
        bf16x8 a = *(const bf16x8*)&uS[ar & 7][k];
        bf16x8 b = *(const bf16x8*)&bpT[ar * EE + k];
        acc = __builtin_amdgcn_mfma_f32_16x16x32_bf16(a, b, acc, 0, 0, 0);
    }
    *(f32x4*)&red[w][lane * 4] = acc;
    __syncthreads();
    if (t < 32) {   // rows 0..7 only
        #pragma unroll
        for (int r = 0; r < 4; ++r) {
            float s = red[0][t * 4 + r] + red[1][t * 4 + r]
                    + red[2][t * 4 + r] + red[3][t * 4 + r];
            int row = (t >> 4) * 4 + r;      // 0..7
            int col = t & 15;
            delta[(r0b + row) * NS + col] = sigmoidf_(s);
        }
    }
}

// ---------------------------------------------------------------- scan pass 1: h_local only (+ folded Dsum)
// grid 1024: et=bid&3 (256 e), c=(bid>>2)&63, b=bid>>8. 1 thread per e.
// u recomputed from staged xs tile via sliding 4-tap window. No y output.
__global__ __launch_bounds__(256) void k_scan1(
    const __bf16* __restrict__ xs, const float* __restrict__ delta,
    const float* __restrict__ A, const float* __restrict__ Bp,
    const float* __restrict__ Wc,
    _Float16* __restrict__ hbuf, float* __restrict__ Dsum)
{
    __shared__ __bf16 xsS[40 * 256]; // 20KB, rows = tok0-3 .. tok0+36
    __shared__ float dls[CL * NS];   // 2KB
    int bid = blockIdx.x;
    int et = bid & 3;
    int c  = (bid >> 2) & (NC - 1);
    int b  = bid >> 8;
    int t  = threadIdx.x;
    int lane = t & 63, w = t >> 6;
    int e0 = et * 256;
    int tok0 = b * LL + c * CL;
    int tokS = tok0 - 3;
    int e  = e0 + t;

    if (w < 2)
        GLOAD(delta + tok0 * NS + w * 256 + lane * 4, dls + w * 256);
    #pragma unroll
    for (int i = 0; i < 5; ++i) {
        int chunk = i * 256 + t;     // row=chunk>>5 in [0,40), col8=chunk&31
        GLOAD(xs + (tokS + (chunk >> 5)) * EE + e0 + (chunk & 31) * 8,
              xsS + (i * 256 + w * 64) * 8);
    }

    float Ae[NS], Bpr[NS];
    #pragma unroll
    for (int q = 0; q < 4; ++q) {
        f32x4 av = *(const f32x4*)&A[e * NS + q * 4];
        f32x4 bv = *(const f32x4*)&Bp[e * NS + q * 4];
        #pragma unroll
        for (int j = 0; j < 4; ++j) {
            Ae[q * 4 + j]  = -__expf(av[j]) * 1.44269504f;
            Bpr[q * 4 + j] = bv[j];
        }
    }
    f32x4 wc = *(const f32x4*)&Wc[e * 4];
    __syncthreads();
    if (c == 0 && t < 96) {          // zero the 3 pre-sequence rows (causal pad)
        int row = t >> 5, c8 = t & 31;
        *(bf16x8*)&xsS[row * 256 + c8 * 8] = (bf16x8){};
    }
    __syncthreads();

    // folded per-chunk delta sums (replaces k_dsum)
    if (et == 0 && t < NS) {
        float s = 0.f;
        #pragma unroll
        for (int l = 0; l < CL; ++l) s += dls[l * NS + t];
        Dsum[(b * NC + c) * NS + t] = s;
    }

    float w0 = (float)xsS[0 * 256 + t];
    float w1 = (float)xsS[1 * 256 + t];
    float w2 = (float)xsS[2 * 256 + t];
    float h[NS] = {};
    for (int l = 0; l < CL; ++l) {
        float w3 = (float)xsS[(l + 3) * 256 + t];
        float a  = w0 * wc[0] + w1 * wc[1] + w2 * wc[2] + w3 * wc[3];
        float uv = a * sigmoidf_(a);
        w0 = w1; w1 = w2; w2 = w3;
        const f32x4* dr = (const f32x4*)&dls[l * NS];
        f32x4 dv[4] = {dr[0], dr[1], dr[2], dr[3]};
        #pragma unroll
        for (int j = 0; j < NS; ++j) {
            float d  = dv[j >> 2][j & 3];
            float ab = __builtin_amdgcn_exp2f(Ae[j] * d);
            h[j] = ab * h[j] + (d * Bpr[j]) * uv;
        }
    }
    int basep = ((b * NC + c) * EE + e) * NS;
    f16x8 h0, h1;
    #pragma unroll
    for (int j = 0; j < 8; ++j) { h0[j] = (_Float16)h[j]; h1[j] = (_Float16)h[8 + j]; }
    *(f16x8*)&hbuf[basep] = h0;
    *(f16x8*)&hbuf[basep + 8] = h1;
}

// ---------------------------------------------------------------- chunk fixup (f16 hbuf)
__global__ __launch_bounds__(256) void k_fix(
    const float* __restrict__ A, const float* __restrict__ Dsum,
    _Float16* __restrict__ hbuf)
{
    int g = blockIdx.x * 256 + threadIdx.x;   // 65536 = B*E*NS
    int b = g >> 14;
    int r = g & 16383;                        // e*NS + n
    int n = r & 15;
    float Ae = -__expf(A[r]) * 1.44269504f;
    float h = 0.f;
    for (int c = 0; c < NC; ++c) {
        int idx = (b * NC + c) * (EE * NS) + r;
        float hl = (float)hbuf[idx];
        float P  = __builtin_amdgcn_exp2f(Ae * Dsum[(b * NC + c) * NS + n]);
        hbuf[idx] = (_Float16)h;              // h_in for chunk c
        h = P * h + hl;
    }
}

// ---------------------------------------------------------------- scan pass 2: full rescan with h_in, sole y producer
__global__ __launch_bounds__(256) void k_scan2(
    const __bf16* __restrict__ xs, const float* __restrict__ delta,
    const float* __restrict__ A, const float* __restrict__ Bp,
    const float* __restrict__ Cp, const float* __restrict__ Dp,
    const float* __restrict__ Wc, const _Float16* __restrict__ hin,
    __bf16* __restrict__ y)
{
    __shared__ __bf16 xsS[40 * 256]; // 20KB
    __shared__ __bf16 yS[CL * 256];  // 16KB
    __shared__ float dls[CL * NS];   // 2KB
    int bid = blockIdx.x;
    int et = bid & 3;
    int c  = (bid >> 2) & (NC - 1);
    int b  = bid >> 8;
    int t  = threadIdx.x;
    int lane = t & 63, w = t >> 6;
    int e0 = et * 256;
    int tok0 = b * LL + c * CL;
    int tokS = tok0 - 3;
    int e  = e0 + t;

    if (w < 2)
        GLOAD(delta + tok0 * NS + w * 256 + lane * 4, dls + w * 256);
    #pragma unroll
    for (int i = 0; i < 5; ++i) {
        int chunk = i * 256 + t;
        GLOAD(xs + (tokS + (chunk >> 5)) * EE + e0 + (chunk & 31) * 8,
              xsS + (i * 256 + w * 64) * 8);
    }

    int basep = ((b * NC + c) * EE + e) * NS;
    f16x8 hv0 = *(const f16x8*)&hin[basep];
    f16x8 hv1 = *(const f16x8*)&hin[basep + 8];
    float Ae[NS], Bpr[NS], Cr[NS], h[NS];
    #pragma unroll
    for (int q = 0; q < 4; ++q) {
        f32x4 av = *(const f32x4*)&A[e * NS + q * 4];
        f32x4 bv = *(const f32x4*)&Bp[e * NS + q * 4];
        f32x4 cv = *(const f32x4*)&Cp[e * NS + q * 4];
        #pragma unroll
        for (int j = 0; j < 4; ++j) {
            int jj = q * 4 + j;
            Ae[jj]  = -__expf(av[j]) * 1.44269504f;
            Bpr[jj] = bv[j];
            Cr[jj]  = cv[j];
            h[jj]   = (jj < 8) ? (float)hv0[jj & 7] : (float)hv1[jj & 7];
        }
    }
    float Dv = Dp[e];
    f32x4 wc = *(const f32x4*)&Wc[e * 4];
    __syncthreads();
    if (c == 0 && t < 96) {
        int row = t >> 5, c8 = t & 31;
        *(bf16x8*)&xsS[row * 256 + c8 * 8] = (bf16x8){};
    }
    __syncthreads();

    float w0 = (float)xsS[0 * 256 + t];
    float w1 = (float)xsS[1 * 256 + t];
    float w2 = (float)xsS[2 * 256 + t];
    for (int l = 0; l < CL; ++l) {
        float w3 = (float)xsS[(l + 3) * 256 + t];
        float a  = w0 * wc[0] + w1 * wc[1] + w2 * wc[2] + w3 * wc[3];
        float uv = a * sigmoidf_(a);
        w0 = w1; w1 = w2; w2 = w3;
        const f32x4* dr = (const f32x4*)&dls[l * NS];
        f32x4 dv[4] = {dr[0], dr[1], dr[2], dr[3]};
        float yv = Dv * uv;
        #pragma unroll
        for (int j = 0; j < NS; ++j) {
            float d  = dv[j >> 2][j & 3];
            float ab = __builtin_amdgcn_exp2f(Ae[j] * d);
            h[j] = ab * h[j] + (d * Bpr[j]) * uv;
            yv += h[j] * Cr[j];
        }
        yS[l * 256 + t] = (__bf16)yv;
    }

    __syncthreads();
    // coalesced y writeout: 4 passes, 16B/thread
    #pragma unroll
    for (int i = 0; i < 4; ++i) {
        int chunk = i * 256 + t;
        *(bf16x8*)&y[(tok0 + (chunk >> 5)) * EE + e0 + (chunk & 31) * 8]
            = *(const bf16x8*)&yS[chunk * 8];
    }
}

// ---------------------------------------------------------------- GEMM2 (m97-style; residual from bf16 xbf)
__global__ __launch_bounds__(256, 2) void k_gemm2(
    const __bf16* __restrict__ Ybf,    // [8192,1024]
    const __bf16* __restrict__ Wobf,   // [512,1024]
    const __bf16* __restrict__ xres,   // [8192,512] bf16
    float* __restrict__ out)
{
    __shared__ __bf16 sA[128 * 64];
    __shared__ __bf16 sB[64 * 64];

    int bid = blockIdx.x;
    int swz = (bid & 7) * 64 + (bid >> 3);   // XCD-chunked (512 % 8 == 0)
    int bm = swz >> 3;          // 0..63
    int bn = swz & 7;           // 0..7

    int t = threadIdx.x;
    int lane = t & 63;
    int w = t >> 6;
    int wm = (w >> 1) * 64;
    int wn = (w & 1) * 32;
    int r15 = lane & 15;
    int kq = lane >> 4;

    const __bf16* Agb = Ybf + (bm * 128) * EE;
    const __bf16* Bgb = Wobf + (bn * 64) * EE;

    f32x4 acc[4][2] = {};

    for (int kt = 0; kt < 16; ++kt) {
        #pragma unroll
        for (int i_ = 0; i_ < 4; ++i_) {
            int c_ = i_ * 256 + t;
            int row_ = c_ >> 3;
            int ss_ = (c_ & 7) ^ (row_ & 7);
            GLOAD(Agb + kt * 64 + row_ * EE + ss_ * 8, sA + (i_ * 256 + w * 64) * 8);
        }
        #pragma unroll
        for (int i_ = 0; i_ < 2; ++i_) {
            int c_ = i_ * 256 + t;
            int row_ = c_ >> 3;
            int ss_ = (c_ & 7) ^ (row_ & 7);
            GLOAD(Bgb + kt * 64 + row_ * EE + ss_ * 8, sB + (i_ * 256 + w * 64) * 8);
        }
        __syncthreads();
        #pragma unroll
        for (int ks = 0; ks < 2; ++ks) {
            int kcs = ks * 4 + kq;
            bf16x8 a[4], bfr[2];
            #pragma unroll
            for (int m = 0; m < 4; ++m) {
                int r = wm + m * 16 + r15;
                a[m] = *(const bf16x8*)&sA[r * 64 + (kcs ^ (r & 7)) * 8];
            }
            #pragma unroll
            for (int n = 0; n < 2; ++n) {
                int r = wn + n * 16 + r15;
                bfr[n] = *(const bf16x8*)&sB[r * 64 + (kcs ^ (r & 7)) * 8];
            }
            #pragma unroll
            for (int m = 0; m < 4; ++m)
                #pragma unroll
                for (int n = 0; n < 2; ++n)
                    acc[m][n] = __builtin_amdgcn_mfma_f32_16x16x32_bf16(a[m], bfr[n], acc[m][n], 0, 0, 0);
        }
        __syncthreads();
    }

    #pragma unroll
    for (int m = 0; m < 4; ++m)
        #pragma unroll
        for (int n = 0; n < 2; ++n)
            #pragma unroll
            for (int r = 0; r < 4; ++r) {
                int row = bm * 128 + wm + m * 16 + (lane >> 4) * 4 + r;
                int col = bn * 64 + wn + n * 16 + r15;
                out[row * DIM + col] = acc[m][n][r] + (float)xres[row * DIM + col];
            }
}

// ---------------------------------------------------------------- launch
// workspace layout (ws_size = 256 MB):
//   [       0,  1048576): woutbf   (tobf -> gemm2)
//   [ 1048576,  1081344): bpT      (tobf -> convdelta)
//   [ 1081344,  1605632): delta    (convdelta -> scan1/scan2)
//   [ 1605632,  1622016): Dsum     (scan1 -> fix)
//   [ 1622016, 18399232): yloc     (scan2 -> gemm2)  [former u region]
//   [18399232, 26787840): xbf      (tobf -> gemm1, gemm2 residual)
//   [26787840, 28884992): winbf    (tobf -> gemm1)
//   [28884992, 45662208): xsbf     (gemm1 -> convdelta/scan1/scan2; read-only after gemm1)
//   [45662208, 54050816): hbuf f16 (scan1 -> fix -> scan2)
extern "C" void kernel_launch(void* const* d_in, const int* in_sizes, int n_in,
                              void* d_out, int out_size, void* d_ws, size_t ws_size,
                              hipStream_t stream) {
    const float* x    = (const float*)d_in[0];
    const float* Win  = (const float*)d_in[1];
    const float* Wc   = (const float*)d_in[2];
    const float* A    = (const float*)d_in[3];
    const float* Bp   = (const float*)d_in[4];
    const float* Cp   = (const float*)d_in[5];
    const float* Dp   = (const float*)d_in[6];
    const float* Wout = (const float*)d_in[7];

    char* ws = (char*)d_ws;
    __bf16* woutbf = (__bf16*)(ws + 0);
    __bf16* bpT    = (__bf16*)(ws + 1048576);
    float*  delta  = (float*)(ws + 1081344);
    float*  Dsum   = (float*)(ws + 1605632);
    __bf16* yloc   = (__bf16*)(ws + 1622016);
    __bf16* xbf    = (__bf16*)(ws + 18399232);
    __bf16* winbf  = (__bf16*)(ws + 26787840);
    __bf16* xsbf   = (__bf16*)(ws + 28884992);
    _Float16* hbuf = (_Float16*)(ws + 45662208);

    k_tobf     <<<5696, 256, 0, stream>>>(x, Win, Wout, Bp, xbf, winbf, woutbf, bpT);
    k_gemm1    <<<1024, 256, 0, stream>>>(xbf, winbf, xsbf);
    k_convdelta<<<1024, 256, 0, stream>>>(xsbf, Wc, bpT, delta);
    k_scan1    <<<1024, 256, 0, stream>>>(xsbf, delta, A, Bp, Wc, hbuf, Dsum);
    k_fix      <<<256, 256, 0, stream>>>(A, Dsum, hbuf);
    k_scan2    <<<1024, 256, 0, stream>>>(xsbf, delta, A, Bp, Cp, Dp, Wc, hbuf, yloc);
    k_gemm2    <<<512, 256, 0, stream>>>(yloc, woutbf, xbf, (float*)d_out);
}

// Round 6
// 133.492 us; speedup vs baseline: 1.0696x; 1.0696x over previous
//
#include <hip/hip_runtime.h>

#define DIM   512
#define EE    1024      // E = expand*dim
#define NS    16        // d_state
#define BB    4
#define LL    2048
#define MM    (BB*LL)   // 8192 token rows
#define NC    64        // scan chunks
#define CL    32        // chunk length (NC*CL == LL)

typedef __bf16 bf16x8 __attribute__((ext_vector_type(8)));
typedef __bf16 bf16x4 __attribute__((ext_vector_type(4)));
typedef float  f32x4  __attribute__((ext_vector_type(4)));
typedef _Float16 f16x8 __attribute__((ext_vector_type(8)));

static __device__ __forceinline__ float sigmoidf_(float x) {
    return 1.0f / (1.0f + __expf(-x));
}

// async global->LDS, 16B per lane; LDS base must be wave-uniform (HW adds lane*16)
#define GLOAD(gp, lp) __builtin_amdgcn_global_load_lds( \
    (const __attribute__((address_space(1))) unsigned int*)(const void*)(gp), \
    (__attribute__((address_space(3))) unsigned int*)(void*)(lp), 16, 0, 0)

// ---------------------------------------------------------------- converts
__global__ __launch_bounds__(256) void k_tobf(
    const float* __restrict__ x, const float* __restrict__ Win,
    const float* __restrict__ Wout, const float* __restrict__ Bp,
    __bf16* __restrict__ xbf, __bf16* __restrict__ winbf,
    __bf16* __restrict__ woutbf, __bf16* __restrict__ bpT)
{
    int g = blockIdx.x * 256 + threadIdx.x;
    const int nx4 = MM * DIM / 4;        // 1048576
    const int nw4 = 2 * EE * DIM / 4;    // 262144
    const int no4 = DIM * EE / 4;        // 131072
    if (g < nx4) {
        f32x4 v = ((const f32x4*)x)[g];
        bf16x4 o; for (int j = 0; j < 4; ++j) o[j] = (__bf16)v[j];
        ((bf16x4*)xbf)[g] = o;
    } else if (g < nx4 + nw4) {
        int i = g - nx4;
        f32x4 v = ((const f32x4*)Win)[i];
        bf16x4 o; for (int j = 0; j < 4; ++j) o[j] = (__bf16)v[j];
        ((bf16x4*)winbf)[i] = o;
    } else if (g < nx4 + nw4 + no4) {
        int i = g - nx4 - nw4;
        f32x4 v = ((const f32x4*)Wout)[i];
        bf16x4 o; for (int j = 0; j < 4; ++j) o[j] = (__bf16)v[j];
        ((bf16x4*)woutbf)[i] = o;
    } else {
        int i = g - nx4 - nw4 - no4;     // [0, 16384)
        int e = i >> 4, n = i & 15;
        bpT[n * EE + e] = (__bf16)Bp[i];
    }
}

// ---------------------------------------------------------------- GEMM1 (m97-style, 128x64 dual-half)
__global__ __launch_bounds__(256, 4) void k_gemm1(
    const __bf16* __restrict__ Abf,   // [8192,512]
    const __bf16* __restrict__ Wbf,   // [2048,512]
    __bf16* __restrict__ xs)          // [8192,1024]
{
    __shared__ __bf16 sA[128 * 64];   // 16KB
    __shared__ __bf16 sB0[64 * 64];   // 8KB
    __shared__ __bf16 sB1[64 * 64];   // 8KB

    int bid = blockIdx.x;
    int swz = (bid & 7) * 128 + (bid >> 3);  // XCD-chunked (1024 % 8 == 0)
    int bm = swz >> 4;          // 0..63
    int bn = swz & 15;          // 0..15

    int t = threadIdx.x;
    int lane = t & 63;
    int w = t >> 6;
    int wm = (w >> 1) * 64;
    int wn = (w & 1) * 32;
    int r15 = lane & 15;
    int kq = lane >> 4;

    const __bf16* Agb  = Abf + (bm * 128) * DIM;
    const __bf16* B0gb = Wbf + (bn * 64) * DIM;
    const __bf16* B1gb = Wbf + (1024 + bn * 64) * DIM;

    f32x4 accx[4][2] = {};
    f32x4 accg[4][2] = {};

    for (int kt = 0; kt < 8; ++kt) {
        #pragma unroll
        for (int i_ = 0; i_ < 4; ++i_) {
            int c_ = i_ * 256 + t;
            int row_ = c_ >> 3;
            int ss_ = (c_ & 7) ^ (row_ & 7);
            GLOAD(Agb + kt * 64 + row_ * DIM + ss_ * 8, sA + (i_ * 256 + w * 64) * 8);
        }
        #pragma unroll
        for (int i_ = 0; i_ < 2; ++i_) {
            int c_ = i_ * 256 + t;
            int row_ = c_ >> 3;
            int ss_ = (c_ & 7) ^ (row_ & 7);
            GLOAD(B0gb + kt * 64 + row_ * DIM + ss_ * 8, sB0 + (i_ * 256 + w * 64) * 8);
            GLOAD(B1gb + kt * 64 + row_ * DIM + ss_ * 8, sB1 + (i_ * 256 + w * 64) * 8);
        }
        __syncthreads();
        #pragma unroll
        for (int ks = 0; ks < 2; ++ks) {
            int kcs = ks * 4 + kq;       // k-slot 0..7
            bf16x8 a[4], b0[2], b1[2];
            #pragma unroll
            for (int m = 0; m < 4; ++m) {
                int r = wm + m * 16 + r15;
                a[m] = *(const bf16x8*)&sA[r * 64 + (kcs ^ (r & 7)) * 8];
            }
            #pragma unroll
            for (int n = 0; n < 2; ++n) {
                int r = wn + n * 16 + r15;
                b0[n] = *(const bf16x8*)&sB0[r * 64 + (kcs ^ (r & 7)) * 8];
                b1[n] = *(const bf16x8*)&sB1[r * 64 + (kcs ^ (r & 7)) * 8];
            }
            #pragma unroll
            for (int m = 0; m < 4; ++m)
                #pragma unroll
                for (int n = 0; n < 2; ++n) {
                    accx[m][n] = __builtin_amdgcn_mfma_f32_16x16x32_bf16(a[m], b0[n], accx[m][n], 0, 0, 0);
                    accg[m][n] = __builtin_amdgcn_mfma_f32_16x16x32_bf16(a[m], b1[n], accg[m][n], 0, 0, 0);
                }
        }
        __syncthreads();
    }

    #pragma unroll
    for (int m = 0; m < 4; ++m)
        #pragma unroll
        for (int n = 0; n < 2; ++n)
            #pragma unroll
            for (int r = 0; r < 4; ++r) {
                int row = bm * 128 + wm + m * 16 + (lane >> 4) * 4 + r;
                int col = bn * 64 + wn + n * 16 + r15;
                float xv = accx[m][n][r];
                float gv = accg[m][n][r];
                xs[row * EE + col] = (__bf16)(xv * sigmoidf_(gv));
            }
}

// ---------------------------------------------------------------- fused depthwise conv + silu + delta projection
__global__ __launch_bounds__(256) void k_convdelta(
    const __bf16* __restrict__ xs, const float* __restrict__ Wc,
    const __bf16* __restrict__ bpT,
    __bf16* __restrict__ u, float* __restrict__ delta)
{
    __shared__ __bf16 uS[8][1032];   // padded: row stride 2064B -> 4-bank offset/row
    __shared__ float red[4][256];
    int bid = blockIdx.x;            // 1024
    int r0b = bid * 8;
    int t = threadIdx.x;
    int cg_ = t & 127, rh = t >> 7;  // rh 0/1 -> 4 rows each
    int e8 = cg_ << 3;
    int rr0 = r0b + rh * 4;
    int l0 = rr0 & (LL - 1);

    f32x4 wj[8];
    #pragma unroll
    for (int j = 0; j < 8; ++j) wj[j] = *(const f32x4*)&Wc[(e8 + j) * 4];
    bf16x8 z = {};
    bf16x8 win[7];
    #pragma unroll
    for (int i = 0; i < 7; ++i) {
        win[i] = (l0 + i >= 3) ? *(const bf16x8*)&xs[(rr0 + i - 3) * EE + e8] : z;
    }
    #pragma unroll
    for (int i = 0; i < 4; ++i) {
        bf16x8 out;
        #pragma unroll
        for (int j = 0; j < 8; ++j) {
            float a = (float)win[i][j] * wj[j][0] + (float)win[i + 1][j] * wj[j][1]
                    + (float)win[i + 2][j] * wj[j][2] + (float)win[i + 3][j] * wj[j][3];
            out[j] = (__bf16)(a * sigmoidf_(a));
        }
        *(bf16x8*)&u[(rr0 + i) * EE + e8] = out;
        *(bf16x8*)&uS[rh * 4 + i][e8] = out;
    }
    __syncthreads();

    // delta phase
    int lane = t & 63, w = t >> 6;
    int ar = lane & 15, kc = (lane >> 4) << 3;
    f32x4 acc = {};
    #pragma unroll
    for (int k0 = 0; k0 < 256; k0 += 32) {
        int k = w * 256 + k0 + kc;
        bf16x8 a = *(const bf16x8*)&uS[ar & 7][k];
        bf16x8 b = *(const bf16x8*)&bpT[ar * EE + k];
        acc = __builtin_amdgcn_mfma_f32_16x16x32_bf16(a, b, acc, 0, 0, 0);
    }
    *(f32x4*)&red[w][lane * 4] = acc;
    __syncthreads();
    if (t < 32) {   // rows 0..7 only
        #pragma unroll
        for (int r = 0; r < 4; ++r) {
            float s = red[0][t * 4 + r] + red[1][t * 4 + r]
                    + red[2][t * 4 + r] + red[3][t * 4 + r];
            int row = (t >> 4) * 4 + r;      // 0..7
            int col = t & 15;
            delta[(r0b + row) * NS + col] = sigmoidf_(s);
        }
    }
}

// ---------------------------------------------------------------- scan pass 1: h_local only (+ folded Dsum)
// grid 1024: et=bid&3 (256 e), c=(bid>>2)&63, b=bid>>8. 1 thread per e, 16 states.
// u tile (16KB) + delta (2KB) staged via global_load_lds. No y output.
__global__ __launch_bounds__(256, 4) void k_scan1(
    const __bf16* __restrict__ u, const float* __restrict__ delta,
    const float* __restrict__ A, const float* __restrict__ Bp,
    _Float16* __restrict__ hbuf, float* __restrict__ Dsum)
{
    __shared__ __bf16 uS[CL * 256];  // 16KB  [l][e]
    __shared__ float dls[CL * NS];   // 2KB
    int bid = blockIdx.x;
    int et = bid & 3;
    int c  = (bid >> 2) & (NC - 1);
    int b  = bid >> 8;
    int t  = threadIdx.x;
    int lane = t & 63, w = t >> 6;
    int e0 = et * 256;
    int tok0 = b * LL + c * CL;
    int e  = e0 + t;

    if (w < 2)
        GLOAD(delta + tok0 * NS + w * 256 + lane * 4, dls + w * 256);
    #pragma unroll
    for (int i = 0; i < 4; ++i) {
        int chunk = i * 256 + t;                 // row=chunk>>5, col8=chunk&31
        GLOAD(u + (tok0 + (chunk >> 5)) * EE + e0 + (chunk & 31) * 8,
              uS + (i * 256 + w * 64) * 8);
    }

    float Ae[NS], Bpr[NS];
    #pragma unroll
    for (int q = 0; q < 4; ++q) {
        f32x4 av = *(const f32x4*)&A[e * NS + q * 4];
        f32x4 bv = *(const f32x4*)&Bp[e * NS + q * 4];
        #pragma unroll
        for (int j = 0; j < 4; ++j) {
            Ae[q * 4 + j]  = -__expf(av[j]) * 1.44269504f;
            Bpr[q * 4 + j] = bv[j];
        }
    }
    __syncthreads();

    // folded per-chunk delta sums (replaces k_dsum)
    if (et == 0 && t < NS) {
        float s = 0.f;
        #pragma unroll
        for (int l = 0; l < CL; ++l) s += dls[l * NS + t];
        Dsum[(b * NC + c) * NS + t] = s;
    }

    float h[NS] = {};
    for (int l = 0; l < CL; ++l) {
        float uv = (float)uS[l * 256 + t];
        const f32x4* dr = (const f32x4*)&dls[l * NS];
        f32x4 dv[4] = {dr[0], dr[1], dr[2], dr[3]};
        #pragma unroll
        for (int j = 0; j < NS; ++j) {
            float d  = dv[j >> 2][j & 3];
            float ab = __builtin_amdgcn_exp2f(Ae[j] * d);
            h[j] = ab * h[j] + (d * Bpr[j]) * uv;
        }
    }
    int basep = ((b * NC + c) * EE + e) * NS;
    f16x8 h0, h1;
    #pragma unroll
    for (int j = 0; j < 8; ++j) { h0[j] = (_Float16)h[j]; h1[j] = (_Float16)h[8 + j]; }
    *(f16x8*)&hbuf[basep] = h0;
    *(f16x8*)&hbuf[basep + 8] = h1;
}

// ---------------------------------------------------------------- chunk fixup (f16 hbuf)
__global__ __launch_bounds__(256) void k_fix(
    const float* __restrict__ A, const float* __restrict__ Dsum,
    _Float16* __restrict__ hbuf)
{
    int g = blockIdx.x * 256 + threadIdx.x;   // 65536 = B*E*NS
    int b = g >> 14;
    int r = g & 16383;                        // e*NS + n
    int n = r & 15;
    float Ae = -__expf(A[r]) * 1.44269504f;
    float h = 0.f;
    for (int c = 0; c < NC; ++c) {
        int idx = (b * NC + c) * (EE * NS) + r;
        float hl = (float)hbuf[idx];
        float P  = __builtin_amdgcn_exp2f(Ae * Dsum[(b * NC + c) * NS + n]);
        hbuf[idx] = (_Float16)h;              // h_in for chunk c
        h = P * h + hl;
    }
}

// ---------------------------------------------------------------- scan pass 2: full rescan with h_in, sole y producer
__global__ __launch_bounds__(256, 4) void k_scan2(
    const __bf16* __restrict__ u, const float* __restrict__ delta,
    const float* __restrict__ A, const float* __restrict__ Bp,
    const float* __restrict__ Cp, const float* __restrict__ Dp,
    const _Float16* __restrict__ hin, __bf16* __restrict__ y)
{
    __shared__ __bf16 uS[CL * 256];  // 16KB
    __shared__ __bf16 yS[CL * 256];  // 16KB
    __shared__ float dls[CL * NS];   // 2KB
    int bid = blockIdx.x;
    int et = bid & 3;
    int c  = (bid >> 2) & (NC - 1);
    int b  = bid >> 8;
    int t  = threadIdx.x;
    int lane = t & 63, w = t >> 6;
    int e0 = et * 256;
    int tok0 = b * LL + c * CL;
    int e  = e0 + t;

    if (w < 2)
        GLOAD(delta + tok0 * NS + w * 256 + lane * 4, dls + w * 256);
    #pragma unroll
    for (int i = 0; i < 4; ++i) {
        int chunk = i * 256 + t;
        GLOAD(u + (tok0 + (chunk >> 5)) * EE + e0 + (chunk & 31) * 8,
              uS + (i * 256 + w * 64) * 8);
    }

    int basep = ((b * NC + c) * EE + e) * NS;
    f16x8 hv0 = *(const f16x8*)&hin[basep];
    f16x8 hv1 = *(const f16x8*)&hin[basep + 8];
    float Ae[NS], Bpr[NS], Cr[NS], h[NS];
    #pragma unroll
    for (int q = 0; q < 4; ++q) {
        f32x4 av = *(const f32x4*)&A[e * NS + q * 4];
        f32x4 bv = *(const f32x4*)&Bp[e * NS + q * 4];
        f32x4 cv = *(const f32x4*)&Cp[e * NS + q * 4];
        #pragma unroll
        for (int j = 0; j < 4; ++j) {
            int jj = q * 4 + j;
            Ae[jj]  = -__expf(av[j]) * 1.44269504f;
            Bpr[jj] = bv[j];
            Cr[jj]  = cv[j];
            h[jj]   = (jj < 8) ? (float)hv0[jj & 7] : (float)hv1[jj & 7];
        }
    }
    float Dv = Dp[e];
    __syncthreads();

    for (int l = 0; l < CL; ++l) {
        float uv = (float)uS[l * 256 + t];
        const f32x4* dr = (const f32x4*)&dls[l * NS];
        f32x4 dv[4] = {dr[0], dr[1], dr[2], dr[3]};
        float yv = Dv * uv;
        #pragma unroll
        for (int j = 0; j < NS; ++j) {
            float d  = dv[j >> 2][j & 3];
            float ab = __builtin_amdgcn_exp2f(Ae[j] * d);
            h[j] = ab * h[j] + (d * Bpr[j]) * uv;
            yv += h[j] * Cr[j];
        }
        yS[l * 256 + t] = (__bf16)yv;
    }

    __syncthreads();
    // coalesced y writeout: 4 passes, 16B/thread
    #pragma unroll
    for (int i = 0; i < 4; ++i) {
        int chunk = i * 256 + t;
        *(bf16x8*)&y[(tok0 + (chunk >> 5)) * EE + e0 + (chunk & 31) * 8]
            = *(const bf16x8*)&yS[chunk * 8];
    }
}

// ---------------------------------------------------------------- GEMM2 (m97-style; residual from bf16 xbf)
__global__ __launch_bounds__(256, 2) void k_gemm2(
    const __bf16* __restrict__ Ybf,    // [8192,1024]
    const __bf16* __restrict__ Wobf,   // [512,1024]
    const __bf16* __restrict__ xres,   // [8192,512] bf16
    float* __restrict__ out)
{
    __shared__ __bf16 sA[128 * 64];
    __shared__ __bf16 sB[64 * 64];

    int bid = blockIdx.x;
    int swz = (bid & 7) * 64 + (bid >> 3);   // XCD-chunked (512 % 8 == 0)
    int bm = swz >> 3;          // 0..63
    int bn = swz & 7;           // 0..7

    int t = threadIdx.x;
    int lane = t & 63;
    int w = t >> 6;
    int wm = (w >> 1) * 64;
    int wn = (w & 1) * 32;
    int r15 = lane & 15;
    int kq = lane >> 4;

    const __bf16* Agb = Ybf + (bm * 128) * EE;
    const __bf16* Bgb = Wobf + (bn * 64) * EE;

    f32x4 acc[4][2] = {};

    for (int kt = 0; kt < 16; ++kt) {
        #pragma unroll
        for (int i_ = 0; i_ < 4; ++i_) {
            int c_ = i_ * 256 + t;
            int row_ = c_ >> 3;
            int ss_ = (c_ & 7) ^ (row_ & 7);
            GLOAD(Agb + kt * 64 + row_ * EE + ss_ * 8, sA + (i_ * 256 + w * 64) * 8);
        }
        #pragma unroll
        for (int i_ = 0; i_ < 2; ++i_) {
            int c_ = i_ * 256 + t;
            int row_ = c_ >> 3;
            int ss_ = (c_ & 7) ^ (row_ & 7);
            GLOAD(Bgb + kt * 64 + row_ * EE + ss_ * 8, sB + (i_ * 256 + w * 64) * 8);
        }
        __syncthreads();
        #pragma unroll
        for (int ks = 0; ks < 2; ++ks) {
            int kcs = ks * 4 + kq;
            bf16x8 a[4], bfr[2];
            #pragma unroll
            for (int m = 0; m < 4; ++m) {
                int r = wm + m * 16 + r15;
                a[m] = *(const bf16x8*)&sA[r * 64 + (kcs ^ (r & 7)) * 8];
            }
            #pragma unroll
            for (int n = 0; n < 2; ++n) {
                int r = wn + n * 16 + r15;
                bfr[n] = *(const bf16x8*)&sB[r * 64 + (kcs ^ (r & 7)) * 8];
            }
            #pragma unroll
            for (int m = 0; m < 4; ++m)
                #pragma unroll
                for (int n = 0; n < 2; ++n)
                    acc[m][n] = __builtin_amdgcn_mfma_f32_16x16x32_bf16(a[m], bfr[n], acc[m][n], 0, 0, 0);
        }
        __syncthreads();
    }

    #pragma unroll
    for (int m = 0; m < 4; ++m)
        #pragma unroll
        for (int n = 0; n < 2; ++n)
            #pragma unroll
            for (int r = 0; r < 4; ++r) {
                int row = bm * 128 + wm + m * 16 + (lane >> 4) * 4 + r;
                int col = bn * 64 + wn + n * 16 + r15;
                out[row * DIM + col] = acc[m][n][r] + (float)xres[row * DIM + col];
            }
}

// ---------------------------------------------------------------- launch
// workspace layout (ws_size = 256 MB):
//   [       0,  1048576): woutbf   (tobf -> gemm2)
//   [ 1048576,  1081344): bpT      (tobf -> convdelta)
//   [ 1081344,  1605632): delta    (convdelta -> scan1/scan2)
//   [ 1605632,  1622016): Dsum     (scan1 -> fix)
//   [ 1622016, 18399232): ubf      (convdelta -> scan1/scan2)
//   [18399232, 26787840): xbf      (tobf -> gemm1, gemm2 residual)
//   [26787840, 28884992): winbf    (tobf -> gemm1)
//   [28884992, 45662208): xsbf (gemm1 -> convdelta); then yloc (scan2 -> gemm2)
//   [45662208, 54050816): hbuf f16 (scan1 -> fix -> scan2)
extern "C" void kernel_launch(void* const* d_in, const int* in_sizes, int n_in,
                              void* d_out, int out_size, void* d_ws, size_t ws_size,
                              hipStream_t stream) {
    const float* x    = (const float*)d_in[0];
    const float* Win  = (const float*)d_in[1];
    const float* Wc   = (const float*)d_in[2];
    const float* A    = (const float*)d_in[3];
    const float* Bp   = (const float*)d_in[4];
    const float* Cp   = (const float*)d_in[5];
    const float* Dp   = (const float*)d_in[6];
    const float* Wout = (const float*)d_in[7];

    char* ws = (char*)d_ws;
    __bf16* woutbf = (__bf16*)(ws + 0);
    __bf16* bpT    = (__bf16*)(ws + 1048576);
    float*  delta  = (float*)(ws + 1081344);
    float*  Dsum   = (float*)(ws + 1605632);
    __bf16* ubf    = (__bf16*)(ws + 1622016);
    __bf16* xbf    = (__bf16*)(ws + 18399232);
    __bf16* winbf  = (__bf16*)(ws + 26787840);
    __bf16* xsbf   = (__bf16*)(ws + 28884992);
    __bf16* yloc   = (__bf16*)(ws + 28884992);  // aliases xsbf (dead after convdelta)
    _Float16* hbuf = (_Float16*)(ws + 45662208);

    k_tobf     <<<5696, 256, 0, stream>>>(x, Win, Wout, Bp, xbf, winbf, woutbf, bpT);
    k_gemm1    <<<1024, 256, 0, stream>>>(xbf, winbf, xsbf);
    k_convdelta<<<1024, 256, 0, stream>>>(xsbf, Wc, bpT, ubf, delta);
    k_scan1    <<<1024, 256, 0, stream>>>(ubf, delta, A, Bp, hbuf, Dsum);
    k_fix      <<<256, 256, 0, stream>>>(A, Dsum, hbuf);
    k_scan2    <<<1024, 256, 0, stream>>>(ubf, delta, A, Bp, Cp, Dp, hbuf, yloc);
    k_gemm2    <<<512, 256, 0, stream>>>(yloc, woutbf, xbf, (float*)d_out);
}

// Round 8
// 127.163 us; speedup vs baseline: 1.1228x; 1.0498x over previous
//
#include <hip/hip_runtime.h>

#define DIM   512
#define EE    1024      // E = expand*dim
#define NS    16        // d_state
#define BB    4
#define LL    2048
#define MM    (BB*LL)   // 8192 token rows
#define NC    64        // scan chunks
#define CL    32        // chunk length (NC*CL == LL)

typedef __bf16 bf16x8 __attribute__((ext_vector_type(8)));
typedef __bf16 bf16x4 __attribute__((ext_vector_type(4)));
typedef float  f32x4  __attribute__((ext_vector_type(4)));
typedef float  f32x2  __attribute__((ext_vector_type(2)));
typedef _Float16 f16x8 __attribute__((ext_vector_type(8)));

static __device__ __forceinline__ float sigmoidf_(float x) {
    return 1.0f / (1.0f + __expf(-x));
}

// async global->LDS, 16B per lane; LDS base must be wave-uniform (HW adds lane*16)
#define GLOAD(gp, lp) __builtin_amdgcn_global_load_lds( \
    (const __attribute__((address_space(1))) unsigned int*)(const void*)(gp), \
    (__attribute__((address_space(3))) unsigned int*)(void*)(lp), 16, 0, 0)

// ---------------------------------------------------------------- converts
__global__ __launch_bounds__(256) void k_tobf(
    const float* __restrict__ x, const float* __restrict__ Win,
    const float* __restrict__ Wout, const float* __restrict__ Bp,
    __bf16* __restrict__ xbf, __bf16* __restrict__ winbf,
    __bf16* __restrict__ woutbf, __bf16* __restrict__ bpT)
{
    int g = blockIdx.x * 256 + threadIdx.x;
    const int nx4 = MM * DIM / 4;        // 1048576
    const int nw4 = 2 * EE * DIM / 4;    // 262144
    const int no4 = DIM * EE / 4;        // 131072
    if (g < nx4) {
        f32x4 v = ((const f32x4*)x)[g];
        bf16x4 o; for (int j = 0; j < 4; ++j) o[j] = (__bf16)v[j];
        ((bf16x4*)xbf)[g] = o;
    } else if (g < nx4 + nw4) {
        int i = g - nx4;
        f32x4 v = ((const f32x4*)Win)[i];
        bf16x4 o; for (int j = 0; j < 4; ++j) o[j] = (__bf16)v[j];
        ((bf16x4*)winbf)[i] = o;
    } else if (g < nx4 + nw4 + no4) {
        int i = g - nx4 - nw4;
        f32x4 v = ((const f32x4*)Wout)[i];
        bf16x4 o; for (int j = 0; j < 4; ++j) o[j] = (__bf16)v[j];
        ((bf16x4*)woutbf)[i] = o;
    } else {
        int i = g - nx4 - nw4 - no4;     // [0, 16384)
        int e = i >> 4, n = i & 15;
        bpT[n * EE + e] = (__bf16)Bp[i];
    }
}

// ---------------------------------------------------------------- GEMM1 (m97-style, 128x64 dual-half)
__global__ __launch_bounds__(256, 4) void k_gemm1(
    const __bf16* __restrict__ Abf,   // [8192,512]
    const __bf16* __restrict__ Wbf,   // [2048,512]
    __bf16* __restrict__ xs)          // [8192,1024]
{
    __shared__ __bf16 sA[128 * 64];   // 16KB
    __shared__ __bf16 sB0[64 * 64];   // 8KB
    __shared__ __bf16 sB1[64 * 64];   // 8KB

    int bid = blockIdx.x;
    int swz = (bid & 7) * 128 + (bid >> 3);  // XCD-chunked (1024 % 8 == 0)
    int bm = swz >> 4;          // 0..63
    int bn = swz & 15;          // 0..15

    int t = threadIdx.x;
    int lane = t & 63;
    int w = t >> 6;
    int wm = (w >> 1) * 64;
    int wn = (w & 1) * 32;
    int r15 = lane & 15;
    int kq = lane >> 4;

    const __bf16* Agb  = Abf + (bm * 128) * DIM;
    const __bf16* B0gb = Wbf + (bn * 64) * DIM;
    const __bf16* B1gb = Wbf + (1024 + bn * 64) * DIM;

    f32x4 accx[4][2] = {};
    f32x4 accg[4][2] = {};

    for (int kt = 0; kt < 8; ++kt) {
        #pragma unroll
        for (int i_ = 0; i_ < 4; ++i_) {
            int c_ = i_ * 256 + t;
            int row_ = c_ >> 3;
            int ss_ = (c_ & 7) ^ (row_ & 7);
            GLOAD(Agb + kt * 64 + row_ * DIM + ss_ * 8, sA + (i_ * 256 + w * 64) * 8);
        }
        #pragma unroll
        for (int i_ = 0; i_ < 2; ++i_) {
            int c_ = i_ * 256 + t;
            int row_ = c_ >> 3;
            int ss_ = (c_ & 7) ^ (row_ & 7);
            GLOAD(B0gb + kt * 64 + row_ * DIM + ss_ * 8, sB0 + (i_ * 256 + w * 64) * 8);
            GLOAD(B1gb + kt * 64 + row_ * DIM + ss_ * 8, sB1 + (i_ * 256 + w * 64) * 8);
        }
        __syncthreads();
        #pragma unroll
        for (int ks = 0; ks < 2; ++ks) {
            int kcs = ks * 4 + kq;       // k-slot 0..7
            bf16x8 a[4], b0[2], b1[2];
            #pragma unroll
            for (int m = 0; m < 4; ++m) {
                int r = wm + m * 16 + r15;
                a[m] = *(const bf16x8*)&sA[r * 64 + (kcs ^ (r & 7)) * 8];
            }
            #pragma unroll
            for (int n = 0; n < 2; ++n) {
                int r = wn + n * 16 + r15;
                b0[n] = *(const bf16x8*)&sB0[r * 64 + (kcs ^ (r & 7)) * 8];
                b1[n] = *(const bf16x8*)&sB1[r * 64 + (kcs ^ (r & 7)) * 8];
            }
            #pragma unroll
            for (int m = 0; m < 4; ++m)
                #pragma unroll
                for (int n = 0; n < 2; ++n) {
                    accx[m][n] = __builtin_amdgcn_mfma_f32_16x16x32_bf16(a[m], b0[n], accx[m][n], 0, 0, 0);
                    accg[m][n] = __builtin_amdgcn_mfma_f32_16x16x32_bf16(a[m], b1[n], accg[m][n], 0, 0, 0);
                }
        }
        __syncthreads();
    }

    #pragma unroll
    for (int m = 0; m < 4; ++m)
        #pragma unroll
        for (int n = 0; n < 2; ++n)
            #pragma unroll
            for (int r = 0; r < 4; ++r) {
                int row = bm * 128 + wm + m * 16 + (lane >> 4) * 4 + r;
                int col = bn * 64 + wn + n * 16 + r15;
                float xv = accx[m][n][r];
                float gv = accg[m][n][r];
                xs[row * EE + col] = (__bf16)(xv * sigmoidf_(gv));
            }
}

// ---------------------------------------------------------------- fused depthwise conv + silu + delta projection
__global__ __launch_bounds__(256) void k_convdelta(
    const __bf16* __restrict__ xs, const float* __restrict__ Wc,
    const __bf16* __restrict__ bpT,
    __bf16* __restrict__ u, float* __restrict__ delta)
{
    __shared__ __bf16 uS[8][1032];   // padded: row stride 2064B -> 4-bank offset/row
    __shared__ float red[4][256];
    int bid = blockIdx.x;            // 1024
    int r0b = bid * 8;
    int t = threadIdx.x;
    int cg_ = t & 127, rh = t >> 7;  // rh 0/1 -> 4 rows each
    int e8 = cg_ << 3;
    int rr0 = r0b + rh * 4;
    int l0 = rr0 & (LL - 1);

    f32x4 wj[8];
    #pragma unroll
    for (int j = 0; j < 8; ++j) wj[j] = *(const f32x4*)&Wc[(e8 + j) * 4];
    bf16x8 z = {};
    bf16x8 win[7];
    #pragma unroll
    for (int i = 0; i < 7; ++i) {
        win[i] = (l0 + i >= 3) ? *(const bf16x8*)&xs[(rr0 + i - 3) * EE + e8] : z;
    }
    #pragma unroll
    for (int i = 0; i < 4; ++i) {
        bf16x8 out;
        #pragma unroll
        for (int j = 0; j < 8; ++j) {
            float a = (float)win[i][j] * wj[j][0] + (float)win[i + 1][j] * wj[j][1]
                    + (float)win[i + 2][j] * wj[j][2] + (float)win[i + 3][j] * wj[j][3];
            out[j] = (__bf16)(a * sigmoidf_(a));
        }
        *(bf16x8*)&u[(rr0 + i) * EE + e8] = out;
        *(bf16x8*)&uS[rh * 4 + i][e8] = out;
    }
    __syncthreads();

    // delta phase
    int lane = t & 63, w = t >> 6;
    int ar = lane & 15, kc = (lane >> 4) << 3;
    f32x4 acc = {};
    #pragma unroll
    for (int k0 = 0; k0 < 256; k0 += 32) {
        int k = w * 256 + k0 + kc;
        bf16x8 a = *(const bf16x8*)&uS[ar & 7][k];
        bf16x8 b = *(const bf16x8*)&bpT[ar * EE + k];
        acc = __builtin_amdgcn_mfma_f32_16x16x32_bf16(a, b, acc, 0, 0, 0);
    }
    *(f32x4*)&red[w][lane * 4] = acc;
    __syncthreads();
    if (t < 32) {   // rows 0..7 only
        #pragma unroll
        for (int r = 0; r < 4; ++r) {
            float s = red[0][t * 4 + r] + red[1][t * 4 + r]
                    + red[2][t * 4 + r] + red[3][t * 4 + r];
            int row = (t >> 4) * 4 + r;      // 0..7
            int col = t & 15;
            delta[(r0b + row) * NS + col] = sigmoidf_(s);
        }
    }
}

// ---------------------------------------------------------------- scan pass 1: h_local only (+ folded Dsum)
// grid 1024: et=bid&3 (256 e), c=(bid>>2)&63, b=bid>>8. 1 thread per e, 16 states.
// States grouped in f32x2 pairs (plain C vector ops -> <2 x float> IR; packed VALU).
__global__ __launch_bounds__(256, 4) void k_scan1(
    const __bf16* __restrict__ u, const float* __restrict__ delta,
    const float* __restrict__ A, const float* __restrict__ Bp,
    _Float16* __restrict__ hbuf, float* __restrict__ Dsum)
{
    __shared__ __bf16 uS[CL * 256];  // 16KB  [l][e]
    __shared__ float dls[CL * NS];   // 2KB
    int bid = blockIdx.x;
    int et = bid & 3;
    int c  = (bid >> 2) & (NC - 1);
    int b  = bid >> 8;
    int t  = threadIdx.x;
    int lane = t & 63, w = t >> 6;
    int e0 = et * 256;
    int tok0 = b * LL + c * CL;
    int e  = e0 + t;

    if (w < 2)
        GLOAD(delta + tok0 * NS + w * 256 + lane * 4, dls + w * 256);
    #pragma unroll
    for (int i = 0; i < 4; ++i) {
        int chunk = i * 256 + t;                 // row=chunk>>5, col8=chunk&31
        GLOAD(u + (tok0 + (chunk >> 5)) * EE + e0 + (chunk & 31) * 8,
              uS + (i * 256 + w * 64) * 8);
    }

    f32x2 Ae2[8], Bpr2[8];
    #pragma unroll
    for (int q = 0; q < 4; ++q) {
        f32x4 av = *(const f32x4*)&A[e * NS + q * 4];
        f32x4 bv = *(const f32x4*)&Bp[e * NS + q * 4];
        #pragma unroll
        for (int j = 0; j < 2; ++j) {
            Ae2[q * 2 + j]  = (f32x2){ -__expf(av[j * 2]) * 1.44269504f,
                                       -__expf(av[j * 2 + 1]) * 1.44269504f };
            Bpr2[q * 2 + j] = (f32x2){ bv[j * 2], bv[j * 2 + 1] };
        }
    }
    __syncthreads();

    // folded per-chunk delta sums (replaces k_dsum)
    if (et == 0 && t < NS) {
        float s = 0.f;
        #pragma unroll
        for (int l = 0; l < CL; ++l) s += dls[l * NS + t];
        Dsum[(b * NC + c) * NS + t] = s;
    }

    f32x2 h2[8] = {};
    for (int l = 0; l < CL; ++l) {
        float uv = (float)uS[l * 256 + t];
        f32x2 uv2 = { uv, uv };
        const f32x2* dr2 = (const f32x2*)&dls[l * NS];
        #pragma unroll
        for (int p = 0; p < 8; ++p) {
            f32x2 d2 = dr2[p];
            f32x2 ea = Ae2[p] * d2;
            f32x2 ab2;
            ab2[0] = __builtin_amdgcn_exp2f(ea[0]);
            ab2[1] = __builtin_amdgcn_exp2f(ea[1]);
            f32x2 x2 = (d2 * Bpr2[p]) * uv2;
            h2[p] = ab2 * h2[p] + x2;        // <2 x float> fma
        }
    }
    int basep = ((b * NC + c) * EE + e) * NS;
    f16x8 h0, h1;
    #pragma unroll
    for (int j = 0; j < 8; ++j) {
        h0[j] = (_Float16)h2[j >> 1][j & 1];
        h1[j] = (_Float16)h2[4 + (j >> 1)][j & 1];
    }
    *(f16x8*)&hbuf[basep] = h0;
    *(f16x8*)&hbuf[basep + 8] = h1;
}

// ---------------------------------------------------------------- chunk fixup (f16 hbuf)
__global__ __launch_bounds__(256) void k_fix(
    const float* __restrict__ A, const float* __restrict__ Dsum,
    _Float16* __restrict__ hbuf)
{
    int g = blockIdx.x * 256 + threadIdx.x;   // 65536 = B*E*NS
    int b = g >> 14;
    int r = g & 16383;                        // e*NS + n
    int n = r & 15;
    float Ae = -__expf(A[r]) * 1.44269504f;
    float h = 0.f;
    for (int c = 0; c < NC; ++c) {
        int idx = (b * NC + c) * (EE * NS) + r;
        float hl = (float)hbuf[idx];
        float P  = __builtin_amdgcn_exp2f(Ae * Dsum[(b * NC + c) * NS + n]);
        hbuf[idx] = (_Float16)h;              // h_in for chunk c
        h = P * h + hl;
    }
}

// ---------------------------------------------------------------- scan pass 2: full rescan with h_in, sole y producer
__global__ __launch_bounds__(256, 4) void k_scan2(
    const __bf16* __restrict__ u, const float* __restrict__ delta,
    const float* __restrict__ A, const float* __restrict__ Bp,
    const float* __restrict__ Cp, const float* __restrict__ Dp,
    const _Float16* __restrict__ hin, __bf16* __restrict__ y)
{
    __shared__ __bf16 uS[CL * 256];  // 16KB
    __shared__ __bf16 yS[CL * 256];  // 16KB
    __shared__ float dls[CL * NS];   // 2KB
    int bid = blockIdx.x;
    int et = bid & 3;
    int c  = (bid >> 2) & (NC - 1);
    int b  = bid >> 8;
    int t  = threadIdx.x;
    int lane = t & 63, w = t >> 6;
    int e0 = et * 256;
    int tok0 = b * LL + c * CL;
    int e  = e0 + t;

    if (w < 2)
        GLOAD(delta + tok0 * NS + w * 256 + lane * 4, dls + w * 256);
    #pragma unroll
    for (int i = 0; i < 4; ++i) {
        int chunk = i * 256 + t;
        GLOAD(u + (tok0 + (chunk >> 5)) * EE + e0 + (chunk & 31) * 8,
              uS + (i * 256 + w * 64) * 8);
    }

    int basep = ((b * NC + c) * EE + e) * NS;
    f16x8 hv0 = *(const f16x8*)&hin[basep];
    f16x8 hv1 = *(const f16x8*)&hin[basep + 8];
    f32x2 Ae2[8], Bpr2[8], Cr2[8], h2[8];
    #pragma unroll
    for (int q = 0; q < 4; ++q) {
        f32x4 av = *(const f32x4*)&A[e * NS + q * 4];
        f32x4 bv = *(const f32x4*)&Bp[e * NS + q * 4];
        f32x4 cv = *(const f32x4*)&Cp[e * NS + q * 4];
        #pragma unroll
        for (int j = 0; j < 2; ++j) {
            int p = q * 2 + j;
            Ae2[p]  = (f32x2){ -__expf(av[j * 2]) * 1.44269504f,
                               -__expf(av[j * 2 + 1]) * 1.44269504f };
            Bpr2[p] = (f32x2){ bv[j * 2], bv[j * 2 + 1] };
            Cr2[p]  = (f32x2){ cv[j * 2], cv[j * 2 + 1] };
        }
    }
    #pragma unroll
    for (int p = 0; p < 8; ++p) {
        h2[p] = (p < 4)
            ? (f32x2){ (float)hv0[(p * 2) & 7], (float)hv0[(p * 2 + 1) & 7] }
            : (f32x2){ (float)hv1[(p * 2) & 7], (float)hv1[(p * 2 + 1) & 7] };
    }
    float Dv = Dp[e];
    __syncthreads();

    for (int l = 0; l < CL; ++l) {
        float uv = (float)uS[l * 256 + t];
        f32x2 uv2 = { uv, uv };
        const f32x2* dr2 = (const f32x2*)&dls[l * NS];
        f32x2 y2 = {};
        #pragma unroll
        for (int p = 0; p < 8; ++p) {
            f32x2 d2 = dr2[p];
            f32x2 ea = Ae2[p] * d2;
            f32x2 ab2;
            ab2[0] = __builtin_amdgcn_exp2f(ea[0]);
            ab2[1] = __builtin_amdgcn_exp2f(ea[1]);
            f32x2 x2 = (d2 * Bpr2[p]) * uv2;
            h2[p] = ab2 * h2[p] + x2;        // h = ab*h + d*B*u
            y2 = y2 + h2[p] * Cr2[p];        // y += h*C
        }
        yS[l * 256 + t] = (__bf16)(Dv * uv + y2[0] + y2[1]);
    }

    __syncthreads();
    // coalesced y writeout: 4 passes, 16B/thread
    #pragma unroll
    for (int i = 0; i < 4; ++i) {
        int chunk = i * 256 + t;
        *(bf16x8*)&y[(tok0 + (chunk >> 5)) * EE + e0 + (chunk & 31) * 8]
            = *(const bf16x8*)&yS[chunk * 8];
    }
}

// ---------------------------------------------------------------- GEMM2 (m97-style; residual from bf16 xbf)
__global__ __launch_bounds__(256, 2) void k_gemm2(
    const __bf16* __restrict__ Ybf,    // [8192,1024]
    const __bf16* __restrict__ Wobf,   // [512,1024]
    const __bf16* __restrict__ xres,   // [8192,512] bf16
    float* __restrict__ out)
{
    __shared__ __bf16 sA[128 * 64];
    __shared__ __bf16 sB[64 * 64];

    int bid = blockIdx.x;
    int swz = (bid & 7) * 64 + (bid >> 3);   // XCD-chunked (512 % 8 == 0)
    int bm = swz >> 3;          // 0..63
    int bn = swz & 7;           // 0..7

    int t = threadIdx.x;
    int lane = t & 63;
    int w = t >> 6;
    int wm = (w >> 1) * 64;
    int wn = (w & 1) * 32;
    int r15 = lane & 15;
    int kq = lane >> 4;

    const __bf16* Agb = Ybf + (bm * 128) * EE;
    const __bf16* Bgb = Wobf + (bn * 64) * EE;

    f32x4 acc[4][2] = {};

    for (int kt = 0; kt < 16; ++kt) {
        #pragma unroll
        for (int i_ = 0; i_ < 4; ++i_) {
            int c_ = i_ * 256 + t;
            int row_ = c_ >> 3;
            int ss_ = (c_ & 7) ^ (row_ & 7);
            GLOAD(Agb + kt * 64 + row_ * EE + ss_ * 8, sA + (i_ * 256 + w * 64) * 8);
        }
        #pragma unroll
        for (int i_ = 0; i_ < 2; ++i_) {
            int c_ = i_ * 256 + t;
            int row_ = c_ >> 3;
            int ss_ = (c_ & 7) ^ (row_ & 7);
            GLOAD(Bgb + kt * 64 + row_ * EE + ss_ * 8, sB + (i_ * 256 + w * 64) * 8);
        }
        __syncthreads();
        #pragma unroll
        for (int ks = 0; ks < 2; ++ks) {
            int kcs = ks * 4 + kq;
            bf16x8 a[4], bfr[2];
            #pragma unroll
            for (int m = 0; m < 4; ++m) {
                int r = wm + m * 16 + r15;
                a[m] = *(const bf16x8*)&sA[r * 64 + (kcs ^ (r & 7)) * 8];
            }
            #pragma unroll
            for (int n = 0; n < 2; ++n) {
                int r = wn + n * 16 + r15;
                bfr[n] = *(const bf16x8*)&sB[r * 64 + (kcs ^ (r & 7)) * 8];
            }
            #pragma unroll
            for (int m = 0; m < 4; ++m)
                #pragma unroll
                for (int n = 0; n < 2; ++n)
                    acc[m][n] = __builtin_amdgcn_mfma_f32_16x16x32_bf16(a[m], bfr[n], acc[m][n], 0, 0, 0);
        }
        __syncthreads();
    }

    #pragma unroll
    for (int m = 0; m < 4; ++m)
        #pragma unroll
        for (int n = 0; n < 2; ++n)
            #pragma unroll
            for (int r = 0; r < 4; ++r) {
                int row = bm * 128 + wm + m * 16 + (lane >> 4) * 4 + r;
                int col = bn * 64 + wn + n * 16 + r15;
                out[row * DIM + col] = acc[m][n][r] + (float)xres[row * DIM + col];
            }
}

// ---------------------------------------------------------------- launch
// workspace layout (ws_size = 256 MB):
//   [       0,  1048576): woutbf   (tobf -> gemm2)
//   [ 1048576,  1081344): bpT      (tobf -> convdelta)
//   [ 1081344,  1605632): delta    (convdelta -> scan1/scan2)
//   [ 1605632,  1622016): Dsum     (scan1 -> fix)
//   [ 1622016, 18399232): ubf      (convdelta -> scan1/scan2)
//   [18399232, 26787840): xbf      (tobf -> gemm1, gemm2 residual)
//   [26787840, 28884992): winbf    (tobf -> gemm1)
//   [28884992, 45662208): xsbf (gemm1 -> convdelta); then yloc (scan2 -> gemm2)
//   [45662208, 54050816): hbuf f16 (scan1 -> fix -> scan2)
extern "C" void kernel_launch(void* const* d_in, const int* in_sizes, int n_in,
                              void* d_out, int out_size, void* d_ws, size_t ws_size,
                              hipStream_t stream) {
    const float* x    = (const float*)d_in[0];
    const float* Win  = (const float*)d_in[1];
    const float* Wc   = (const float*)d_in[2];
    const float* A    = (const float*)d_in[3];
    const float* Bp   = (const float*)d_in[4];
    const float* Cp   = (const float*)d_in[5];
    const float* Dp   = (const float*)d_in[6];
    const float* Wout = (const float*)d_in[7];

    char* ws = (char*)d_ws;
    __bf16* woutbf = (__bf16*)(ws + 0);
    __bf16* bpT    = (__bf16*)(ws + 1048576);
    float*  delta  = (float*)(ws + 1081344);
    float*  Dsum   = (float*)(ws + 1605632);
    __bf16* ubf    = (__bf16*)(ws + 1622016);
    __bf16* xbf    = (__bf16*)(ws + 18399232);
    __bf16* winbf  = (__bf16*)(ws + 26787840);
    __bf16* xsbf   = (__bf16*)(ws + 28884992);
    __bf16* yloc   = (__bf16*)(ws + 28884992);  // aliases xsbf (dead after convdelta)
    _Float16* hbuf = (_Float16*)(ws + 45662208);

    k_tobf     <<<5696, 256, 0, stream>>>(x, Win, Wout, Bp, xbf, winbf, woutbf, bpT);
    k_gemm1    <<<1024, 256, 0, stream>>>(xbf, winbf, xsbf);
    k_convdelta<<<1024, 256, 0, stream>>>(xsbf, Wc, bpT, ubf, delta);
    k_scan1    <<<1024, 256, 0, stream>>>(ubf, delta, A, Bp, hbuf, Dsum);
    k_fix      <<<256, 256, 0, stream>>>(A, Dsum, hbuf);
    k_scan2    <<<1024, 256, 0, stream>>>(ubf, delta, A, Bp, Cp, Dp, hbuf, yloc);
    k_gemm2    <<<512, 256, 0, stream>>>(yloc, woutbf, xbf, (float*)d_out);
}

// Round 9
// 122.136 us; speedup vs baseline: 1.1691x; 1.0412x over previous
//
#include <hip/hip_runtime.h>

#define DIM   512
#define EE    1024      // E = expand*dim
#define NS    16        // d_state
#define BB    4
#define LL    2048
#define MM    (BB*LL)   // 8192 token rows
#define NC    64        // scan chunks
#define CL    32        // chunk length (NC*CL == LL)

typedef __bf16 bf16x8 __attribute__((ext_vector_type(8)));
typedef __bf16 bf16x4 __attribute__((ext_vector_type(4)));
typedef float  f32x4  __attribute__((ext_vector_type(4)));
typedef float  f32x2  __attribute__((ext_vector_type(2)));
typedef _Float16 f16x8 __attribute__((ext_vector_type(8)));

static __device__ __forceinline__ float sigmoidf_(float x) {
    return 1.0f / (1.0f + __expf(-x));
}

// async global->LDS, 16B per lane; LDS base must be wave-uniform (HW adds lane*16)
#define GLOAD(gp, lp) __builtin_amdgcn_global_load_lds( \
    (const __attribute__((address_space(1))) unsigned int*)(const void*)(gp), \
    (__attribute__((address_space(3))) unsigned int*)(void*)(lp), 16, 0, 0)

// ---------------------------------------------------------------- converts
__global__ __launch_bounds__(256) void k_tobf(
    const float* __restrict__ x, const float* __restrict__ Win,
    const float* __restrict__ Wout, const float* __restrict__ Bp,
    __bf16* __restrict__ xbf, __bf16* __restrict__ winbf,
    __bf16* __restrict__ woutbf, __bf16* __restrict__ bpT)
{
    int g = blockIdx.x * 256 + threadIdx.x;
    const int nx4 = MM * DIM / 4;        // 1048576
    const int nw4 = 2 * EE * DIM / 4;    // 262144
    const int no4 = DIM * EE / 4;        // 131072
    if (g < nx4) {
        f32x4 v = ((const f32x4*)x)[g];
        bf16x4 o; for (int j = 0; j < 4; ++j) o[j] = (__bf16)v[j];
        ((bf16x4*)xbf)[g] = o;
    } else if (g < nx4 + nw4) {
        int i = g - nx4;
        f32x4 v = ((const f32x4*)Win)[i];
        bf16x4 o; for (int j = 0; j < 4; ++j) o[j] = (__bf16)v[j];
        ((bf16x4*)winbf)[i] = o;
    } else if (g < nx4 + nw4 + no4) {
        int i = g - nx4 - nw4;
        f32x4 v = ((const f32x4*)Wout)[i];
        bf16x4 o; for (int j = 0; j < 4; ++j) o[j] = (__bf16)v[j];
        ((bf16x4*)woutbf)[i] = o;
    } else {
        int i = g - nx4 - nw4 - no4;     // [0, 16384)
        int e = i >> 4, n = i & 15;
        bpT[n * EE + e] = (__bf16)Bp[i];
    }
}

// ---------------------------------------------------------------- GEMM1 (128x128 dual-half, grid 512)
// Each block: 128 rows x 128 cols of xs AND 128 cols of gate (same col index +1024).
// 87 flop/staged-byte vs 64 for the 128x64 variant.
__global__ __launch_bounds__(256, 2) void k_gemm1(
    const __bf16* __restrict__ Abf,   // [8192,512]
    const __bf16* __restrict__ Wbf,   // [2048,512]
    __bf16* __restrict__ xs)          // [8192,1024]
{
    __shared__ __bf16 sA[128 * 64];   // 16KB
    __shared__ __bf16 sB0[128 * 64];  // 16KB
    __shared__ __bf16 sB1[128 * 64];  // 16KB

    int bid = blockIdx.x;
    int swz = (bid & 7) * 64 + (bid >> 3);   // XCD-chunked (512 % 8 == 0)
    int bm = swz >> 3;          // 0..63
    int bn = swz & 7;           // 0..7

    int t = threadIdx.x;
    int lane = t & 63;
    int w = t >> 6;
    int wm = (w >> 1) * 64;
    int wn = (w & 1) * 64;
    int r15 = lane & 15;
    int kq = lane >> 4;

    const __bf16* Agb  = Abf + (bm * 128) * DIM;
    const __bf16* B0gb = Wbf + (bn * 128) * DIM;
    const __bf16* B1gb = Wbf + (1024 + bn * 128) * DIM;

    f32x4 accx[4][4] = {};
    f32x4 accg[4][4] = {};

    for (int kt = 0; kt < 8; ++kt) {
        #pragma unroll
        for (int i_ = 0; i_ < 4; ++i_) {
            int c_ = i_ * 256 + t;
            int row_ = c_ >> 3;
            int ss_ = (c_ & 7) ^ (row_ & 7);
            GLOAD(Agb  + kt * 64 + row_ * DIM + ss_ * 8, sA  + (i_ * 256 + w * 64) * 8);
            GLOAD(B0gb + kt * 64 + row_ * DIM + ss_ * 8, sB0 + (i_ * 256 + w * 64) * 8);
            GLOAD(B1gb + kt * 64 + row_ * DIM + ss_ * 8, sB1 + (i_ * 256 + w * 64) * 8);
        }
        __syncthreads();
        #pragma unroll
        for (int ks = 0; ks < 2; ++ks) {
            int kcs = ks * 4 + kq;       // k-slot 0..7
            bf16x8 a[4], b0[4], b1[4];
            #pragma unroll
            for (int m = 0; m < 4; ++m) {
                int r = wm + m * 16 + r15;
                a[m] = *(const bf16x8*)&sA[r * 64 + (kcs ^ (r & 7)) * 8];
            }
            #pragma unroll
            for (int n = 0; n < 4; ++n) {
                int r = wn + n * 16 + r15;
                b0[n] = *(const bf16x8*)&sB0[r * 64 + (kcs ^ (r & 7)) * 8];
                b1[n] = *(const bf16x8*)&sB1[r * 64 + (kcs ^ (r & 7)) * 8];
            }
            #pragma unroll
            for (int m = 0; m < 4; ++m)
                #pragma unroll
                for (int n = 0; n < 4; ++n) {
                    accx[m][n] = __builtin_amdgcn_mfma_f32_16x16x32_bf16(a[m], b0[n], accx[m][n], 0, 0, 0);
                    accg[m][n] = __builtin_amdgcn_mfma_f32_16x16x32_bf16(a[m], b1[n], accg[m][n], 0, 0, 0);
                }
        }
        __syncthreads();
    }

    #pragma unroll
    for (int m = 0; m < 4; ++m)
        #pragma unroll
        for (int n = 0; n < 4; ++n)
            #pragma unroll
            for (int r = 0; r < 4; ++r) {
                int row = bm * 128 + wm + m * 16 + (lane >> 4) * 4 + r;
                int col = bn * 128 + wn + n * 16 + r15;
                float xv = accx[m][n][r];
                float gv = accg[m][n][r];
                xs[row * EE + col] = (__bf16)(xv * sigmoidf_(gv));
            }
}

// ---------------------------------------------------------------- fused depthwise conv + silu + delta projection
__global__ __launch_bounds__(256) void k_convdelta(
    const __bf16* __restrict__ xs, const float* __restrict__ Wc,
    const __bf16* __restrict__ bpT,
    __bf16* __restrict__ u, float* __restrict__ delta)
{
    __shared__ __bf16 uS[8][1032];   // padded: row stride 2064B -> 4-bank offset/row
    __shared__ float red[4][256];
    int bid = blockIdx.x;            // 1024
    int r0b = bid * 8;
    int t = threadIdx.x;
    int cg_ = t & 127, rh = t >> 7;  // rh 0/1 -> 4 rows each
    int e8 = cg_ << 3;
    int rr0 = r0b + rh * 4;
    int l0 = rr0 & (LL - 1);

    f32x4 wj[8];
    #pragma unroll
    for (int j = 0; j < 8; ++j) wj[j] = *(const f32x4*)&Wc[(e8 + j) * 4];
    bf16x8 z = {};
    bf16x8 win[7];
    #pragma unroll
    for (int i = 0; i < 7; ++i) {
        win[i] = (l0 + i >= 3) ? *(const bf16x8*)&xs[(rr0 + i - 3) * EE + e8] : z;
    }
    #pragma unroll
    for (int i = 0; i < 4; ++i) {
        bf16x8 out;
        #pragma unroll
        for (int j = 0; j < 8; ++j) {
            float a = (float)win[i][j] * wj[j][0] + (float)win[i + 1][j] * wj[j][1]
                    + (float)win[i + 2][j] * wj[j][2] + (float)win[i + 3][j] * wj[j][3];
            out[j] = (__bf16)(a * sigmoidf_(a));
        }
        *(bf16x8*)&u[(rr0 + i) * EE + e8] = out;
        *(bf16x8*)&uS[rh * 4 + i][e8] = out;
    }
    __syncthreads();

    // delta phase
    int lane = t & 63, w = t >> 6;
    int ar = lane & 15, kc = (lane >> 4) << 3;
    f32x4 acc = {};
    #pragma unroll
    for (int k0 = 0; k0 < 256; k0 += 32) {
        int k = w * 256 + k0 + kc;
        bf16x8 a = *(const bf16x8*)&uS[ar & 7][k];
        bf16x8 b = *(const bf16x8*)&bpT[ar * EE + k];
        acc = __builtin_amdgcn_mfma_f32_16x16x32_bf16(a, b, acc, 0, 0, 0);
    }
    *(f32x4*)&red[w][lane * 4] = acc;
    __syncthreads();
    if (t < 32) {   // rows 0..7 only
        #pragma unroll
        for (int r = 0; r < 4; ++r) {
            float s = red[0][t * 4 + r] + red[1][t * 4 + r]
                    + red[2][t * 4 + r] + red[3][t * 4 + r];
            int row = (t >> 4) * 4 + r;      // 0..7
            int col = t & 15;
            delta[(r0b + row) * NS + col] = sigmoidf_(s);
        }
    }
}

// ---------------------------------------------------------------- scan pass 1: h_local only (+ folded Dsum)
// grid 1024: et=bid&3 (256 e), c=(bid>>2)&63, b=bid>>8. 1 thread per e, 16 states.
// States grouped in f32x2 pairs (plain C vector ops -> <2 x float> IR; packed VALU).
__global__ __launch_bounds__(256, 4) void k_scan1(
    const __bf16* __restrict__ u, const float* __restrict__ delta,
    const float* __restrict__ A, const float* __restrict__ Bp,
    _Float16* __restrict__ hbuf, float* __restrict__ Dsum)
{
    __shared__ __bf16 uS[CL * 256];  // 16KB  [l][e]
    __shared__ float dls[CL * NS];   // 2KB
    int bid = blockIdx.x;
    int et = bid & 3;
    int c  = (bid >> 2) & (NC - 1);
    int b  = bid >> 8;
    int t  = threadIdx.x;
    int lane = t & 63, w = t >> 6;
    int e0 = et * 256;
    int tok0 = b * LL + c * CL;
    int e  = e0 + t;

    if (w < 2)
        GLOAD(delta + tok0 * NS + w * 256 + lane * 4, dls + w * 256);
    #pragma unroll
    for (int i = 0; i < 4; ++i) {
        int chunk = i * 256 + t;                 // row=chunk>>5, col8=chunk&31
        GLOAD(u + (tok0 + (chunk >> 5)) * EE + e0 + (chunk & 31) * 8,
              uS + (i * 256 + w * 64) * 8);
    }

    f32x2 Ae2[8], Bpr2[8];
    #pragma unroll
    for (int q = 0; q < 4; ++q) {
        f32x4 av = *(const f32x4*)&A[e * NS + q * 4];
        f32x4 bv = *(const f32x4*)&Bp[e * NS + q * 4];
        #pragma unroll
        for (int j = 0; j < 2; ++j) {
            Ae2[q * 2 + j]  = (f32x2){ -__expf(av[j * 2]) * 1.44269504f,
                                       -__expf(av[j * 2 + 1]) * 1.44269504f };
            Bpr2[q * 2 + j] = (f32x2){ bv[j * 2], bv[j * 2 + 1] };
        }
    }
    __syncthreads();

    // folded per-chunk delta sums (replaces k_dsum)
    if (et == 0 && t < NS) {
        float s = 0.f;
        #pragma unroll
        for (int l = 0; l < CL; ++l) s += dls[l * NS + t];
        Dsum[(b * NC + c) * NS + t] = s;
    }

    f32x2 h2[8] = {};
    for (int l = 0; l < CL; ++l) {
        float uv = (float)uS[l * 256 + t];
        f32x2 uv2 = { uv, uv };
        const f32x2* dr2 = (const f32x2*)&dls[l * NS];
        #pragma unroll
        for (int p = 0; p < 8; ++p) {
            f32x2 d2 = dr2[p];
            f32x2 ea = Ae2[p] * d2;
            f32x2 ab2;
            ab2[0] = __builtin_amdgcn_exp2f(ea[0]);
            ab2[1] = __builtin_amdgcn_exp2f(ea[1]);
            f32x2 x2 = (d2 * Bpr2[p]) * uv2;
            h2[p] = ab2 * h2[p] + x2;        // <2 x float> fma
        }
    }
    int basep = ((b * NC + c) * EE + e) * NS;
    f16x8 h0, h1;
    #pragma unroll
    for (int j = 0; j < 8; ++j) {
        h0[j] = (_Float16)h2[j >> 1][j & 1];
        h1[j] = (_Float16)h2[4 + (j >> 1)][j & 1];
    }
    *(f16x8*)&hbuf[basep] = h0;
    *(f16x8*)&hbuf[basep + 8] = h1;
}

// ---------------------------------------------------------------- chunk fixup (f16 hbuf)
__global__ __launch_bounds__(256) void k_fix(
    const float* __restrict__ A, const float* __restrict__ Dsum,
    _Float16* __restrict__ hbuf)
{
    int g = blockIdx.x * 256 + threadIdx.x;   // 65536 = B*E*NS
    int b = g >> 14;
    int r = g & 16383;                        // e*NS + n
    int n = r & 15;
    float Ae = -__expf(A[r]) * 1.44269504f;
    float h = 0.f;
    for (int c = 0; c < NC; ++c) {
        int idx = (b * NC + c) * (EE * NS) + r;
        float hl = (float)hbuf[idx];
        float P  = __builtin_amdgcn_exp2f(Ae * Dsum[(b * NC + c) * NS + n]);
        hbuf[idx] = (_Float16)h;              // h_in for chunk c
        h = P * h + hl;
    }
}

// ---------------------------------------------------------------- scan pass 2: full rescan with h_in, sole y producer
__global__ __launch_bounds__(256, 4) void k_scan2(
    const __bf16* __restrict__ u, const float* __restrict__ delta,
    const float* __restrict__ A, const float* __restrict__ Bp,
    const float* __restrict__ Cp, const float* __restrict__ Dp,
    const _Float16* __restrict__ hin, __bf16* __restrict__ y)
{
    __shared__ __bf16 uS[CL * 256];  // 16KB
    __shared__ __bf16 yS[CL * 256];  // 16KB
    __shared__ float dls[CL * NS];   // 2KB
    int bid = blockIdx.x;
    int et = bid & 3;
    int c  = (bid >> 2) & (NC - 1);
    int b  = bid >> 8;
    int t  = threadIdx.x;
    int lane = t & 63, w = t >> 6;
    int e0 = et * 256;
    int tok0 = b * LL + c * CL;
    int e  = e0 + t;

    if (w < 2)
        GLOAD(delta + tok0 * NS + w * 256 + lane * 4, dls + w * 256);
    #pragma unroll
    for (int i = 0; i < 4; ++i) {
        int chunk = i * 256 + t;
        GLOAD(u + (tok0 + (chunk >> 5)) * EE + e0 + (chunk & 31) * 8,
              uS + (i * 256 + w * 64) * 8);
    }

    int basep = ((b * NC + c) * EE + e) * NS;
    f16x8 hv0 = *(const f16x8*)&hin[basep];
    f16x8 hv1 = *(const f16x8*)&hin[basep + 8];
    f32x2 Ae2[8], Bpr2[8], Cr2[8], h2[8];
    #pragma unroll
    for (int q = 0; q < 4; ++q) {
        f32x4 av = *(const f32x4*)&A[e * NS + q * 4];
        f32x4 bv = *(const f32x4*)&Bp[e * NS + q * 4];
        f32x4 cv = *(const f32x4*)&Cp[e * NS + q * 4];
        #pragma unroll
        for (int j = 0; j < 2; ++j) {
            int p = q * 2 + j;
            Ae2[p]  = (f32x2){ -__expf(av[j * 2]) * 1.44269504f,
                               -__expf(av[j * 2 + 1]) * 1.44269504f };
            Bpr2[p] = (f32x2){ bv[j * 2], bv[j * 2 + 1] };
            Cr2[p]  = (f32x2){ cv[j * 2], cv[j * 2 + 1] };
        }
    }
    #pragma unroll
    for (int p = 0; p < 8; ++p) {
        h2[p] = (p < 4)
            ? (f32x2){ (float)hv0[(p * 2) & 7], (float)hv0[(p * 2 + 1) & 7] }
            : (f32x2){ (float)hv1[(p * 2) & 7], (float)hv1[(p * 2 + 1) & 7] };
    }
    float Dv = Dp[e];
    __syncthreads();

    for (int l = 0; l < CL; ++l) {
        float uv = (float)uS[l * 256 + t];
        f32x2 uv2 = { uv, uv };
        const f32x2* dr2 = (const f32x2*)&dls[l * NS];
        f32x2 y2 = {};
        #pragma unroll
        for (int p = 0; p < 8; ++p) {
            f32x2 d2 = dr2[p];
            f32x2 ea = Ae2[p] * d2;
            f32x2 ab2;
            ab2[0] = __builtin_amdgcn_exp2f(ea[0]);
            ab2[1] = __builtin_amdgcn_exp2f(ea[1]);
            f32x2 x2 = (d2 * Bpr2[p]) * uv2;
            h2[p] = ab2 * h2[p] + x2;        // h = ab*h + d*B*u
            y2 = y2 + h2[p] * Cr2[p];        // y += h*C
        }
        yS[l * 256 + t] = (__bf16)(Dv * uv + y2[0] + y2[1]);
    }

    __syncthreads();
    // coalesced y writeout: 4 passes, 16B/thread
    #pragma unroll
    for (int i = 0; i < 4; ++i) {
        int chunk = i * 256 + t;
        *(bf16x8*)&y[(tok0 + (chunk >> 5)) * EE + e0 + (chunk & 31) * 8]
            = *(const bf16x8*)&yS[chunk * 8];
    }
}

// ---------------------------------------------------------------- GEMM2 (m97-style; residual from bf16 xbf)
__global__ __launch_bounds__(256, 2) void k_gemm2(
    const __bf16* __restrict__ Ybf,    // [8192,1024]
    const __bf16* __restrict__ Wobf,   // [512,1024]
    const __bf16* __restrict__ xres,   // [8192,512] bf16
    float* __restrict__ out)
{
    __shared__ __bf16 sA[128 * 64];
    __shared__ __bf16 sB[64 * 64];

    int bid = blockIdx.x;
    int swz = (bid & 7) * 64 + (bid >> 3);   // XCD-chunked (512 % 8 == 0)
    int bm = swz >> 3;          // 0..63
    int bn = swz & 7;           // 0..7

    int t = threadIdx.x;
    int lane = t & 63;
    int w = t >> 6;
    int wm = (w >> 1) * 64;
    int wn = (w & 1) * 32;
    int r15 = lane & 15;
    int kq = lane >> 4;

    const __bf16* Agb = Ybf + (bm * 128) * EE;
    const __bf16* Bgb = Wobf + (bn * 64) * EE;

    f32x4 acc[4][2] = {};

    for (int kt = 0; kt < 16; ++kt) {
        #pragma unroll
        for (int i_ = 0; i_ < 4; ++i_) {
            int c_ = i_ * 256 + t;
            int row_ = c_ >> 3;
            int ss_ = (c_ & 7) ^ (row_ & 7);
            GLOAD(Agb + kt * 64 + row_ * EE + ss_ * 8, sA + (i_ * 256 + w * 64) * 8);
        }
        #pragma unroll
        for (int i_ = 0; i_ < 2; ++i_) {
            int c_ = i_ * 256 + t;
            int row_ = c_ >> 3;
            int ss_ = (c_ & 7) ^ (row_ & 7);
            GLOAD(Bgb + kt * 64 + row_ * EE + ss_ * 8, sB + (i_ * 256 + w * 64) * 8);
        }
        __syncthreads();
        #pragma unroll
        for (int ks = 0; ks < 2; ++ks) {
            int kcs = ks * 4 + kq;
            bf16x8 a[4], bfr[2];
            #pragma unroll
            for (int m = 0; m < 4; ++m) {
                int r = wm + m * 16 + r15;
                a[m] = *(const bf16x8*)&sA[r * 64 + (kcs ^ (r & 7)) * 8];
            }
            #pragma unroll
            for (int n = 0; n < 2; ++n) {
                int r = wn + n * 16 + r15;
                bfr[n] = *(const bf16x8*)&sB[r * 64 + (kcs ^ (r & 7)) * 8];
            }
            #pragma unroll
            for (int m = 0; m < 4; ++m)
                #pragma unroll
                for (int n = 0; n < 2; ++n)
                    acc[m][n] = __builtin_amdgcn_mfma_f32_16x16x32_bf16(a[m], bfr[n], acc[m][n], 0, 0, 0);
        }
        __syncthreads();
    }

    #pragma unroll
    for (int m = 0; m < 4; ++m)
        #pragma unroll
        for (int n = 0; n < 2; ++n)
            #pragma unroll
            for (int r = 0; r < 4; ++r) {
                int row = bm * 128 + wm + m * 16 + (lane >> 4) * 4 + r;
                int col = bn * 64 + wn + n * 16 + r15;
                out[row * DIM + col] = acc[m][n][r] + (float)xres[row * DIM + col];
            }
}

// ---------------------------------------------------------------- launch
// workspace layout (ws_size = 256 MB):
//   [       0,  1048576): woutbf   (tobf -> gemm2)
//   [ 1048576,  1081344): bpT      (tobf -> convdelta)
//   [ 1081344,  1605632): delta    (convdelta -> scan1/scan2)
//   [ 1605632,  1622016): Dsum     (scan1 -> fix)
//   [ 1622016, 18399232): ubf      (convdelta -> scan1/scan2)
//   [18399232, 26787840): xbf      (tobf -> gemm1, gemm2 residual)
//   [26787840, 28884992): winbf    (tobf -> gemm1)
//   [28884992, 45662208): xsbf (gemm1 -> convdelta); then yloc (scan2 -> gemm2)
//   [45662208, 54050816): hbuf f16 (scan1 -> fix -> scan2)
extern "C" void kernel_launch(void* const* d_in, const int* in_sizes, int n_in,
                              void* d_out, int out_size, void* d_ws, size_t ws_size,
                              hipStream_t stream) {
    const float* x    = (const float*)d_in[0];
    const float* Win  = (const float*)d_in[1];
    const float* Wc   = (const float*)d_in[2];
    const float* A    = (const float*)d_in[3];
    const float* Bp   = (const float*)d_in[4];
    const float* Cp   = (const float*)d_in[5];
    const float* Dp   = (const float*)d_in[6];
    const float* Wout = (const float*)d_in[7];

    char* ws = (char*)d_ws;
    __bf16* woutbf = (__bf16*)(ws + 0);
    __bf16* bpT    = (__bf16*)(ws + 1048576);
    float*  delta  = (float*)(ws + 1081344);
    float*  Dsum   = (float*)(ws + 1605632);
    __bf16* ubf    = (__bf16*)(ws + 1622016);
    __bf16* xbf    = (__bf16*)(ws + 18399232);
    __bf16* winbf  = (__bf16*)(ws + 26787840);
    __bf16* xsbf   = (__bf16*)(ws + 28884992);
    __bf16* yloc   = (__bf16*)(ws + 28884992);  // aliases xsbf (dead after convdelta)
    _Float16* hbuf = (_Float16*)(ws + 45662208);

    k_tobf     <<<5696, 256, 0, stream>>>(x, Win, Wout, Bp, xbf, winbf, woutbf, bpT);
    k_gemm1    <<<512, 256, 0, stream>>>(xbf, winbf, xsbf);
    k_convdelta<<<1024, 256, 0, stream>>>(xsbf, Wc, bpT, ubf, delta);
    k_scan1    <<<1024, 256, 0, stream>>>(ubf, delta, A, Bp, hbuf, Dsum);
    k_fix      <<<256, 256, 0, stream>>>(A, Dsum, hbuf);
    k_scan2    <<<1024, 256, 0, stream>>>(ubf, delta, A, Bp, Cp, Dp, hbuf, yloc);
    k_gemm2    <<<512, 256, 0, stream>>>(yloc, woutbf, xbf, (float*)d_out);
}